// Round 8
// baseline (5228.246 us; speedup 1.0000x reference)
//
#include <hip/hip_runtime.h>

typedef unsigned int u32;
typedef unsigned short u16;
typedef unsigned long long u64;
typedef _Float16 f16;
typedef f16 f16x2 __attribute__((ext_vector_type(2)));
typedef u32 u32x4 __attribute__((ext_vector_type(4)));   // asm-pinnable quad

__device__ __forceinline__ float fdot2(u32 a, u32 b, float c) {
#if __has_builtin(__builtin_amdgcn_fdot2)
    return __builtin_amdgcn_fdot2(__builtin_bit_cast(f16x2, a),
                                  __builtin_bit_cast(f16x2, b), c, false);
#else
    f16x2 av = __builtin_bit_cast(f16x2, a), bv = __builtin_bit_cast(f16x2, b);
    c += (float)av[0] * (float)bv[0];
    c += (float)av[1] * (float)bv[1];
    return c;
#endif
}

__device__ __forceinline__ u32 pack2h(float a, float b) {
    f16x2 h; h[0] = (f16)a; h[1] = (f16)b;
    return __builtin_bit_cast(u32, h);
}
__device__ __forceinline__ float h2f(u16 x) { return (float)__builtin_bit_cast(f16, x); }
__device__ __forceinline__ u16 f2h(float x) { f16 h = (f16)x; return __builtin_bit_cast(u16, h); }

__device__ __forceinline__ float fexp(float x) {
#if __has_builtin(__builtin_amdgcn_exp2f)
    return __builtin_amdgcn_exp2f(x * 1.44269504088896f);
#else
    return __expf(x);
#endif
}
__device__ __forceinline__ float frcp(float x) {
#if __has_builtin(__builtin_amdgcn_rcpf)
    return __builtin_amdgcn_rcpf(x);
#else
    return 1.0f / x;
#endif
}
__device__ __forceinline__ float fsigmoid(float x) { return frcp(1.0f + fexp(-x)); }
__device__ __forceinline__ float ftanh_pos(float x) { return 1.0f - 2.0f * frcp(fexp(2.0f * x) + 1.0f); }

// ---------------------------------------------------------------------------
// K0: pack weights to f16 pairs. (unchanged)
//   WpkT[d][p] = (Wi[d][2p], Wi[d][2p+1])   d<512, p<256   (row-major rows)
//   Wypk[p][d] = (Wy[d][2p], Wy[d][2p+1])   (K2 epilogue layout)
// ---------------------------------------------------------------------------
__global__ __launch_bounds__(256) void k0_pack(const float* __restrict__ Wi,
                                               const float* __restrict__ Wy,
                                               u32* __restrict__ WpkT,
                                               u32* __restrict__ Wypk) {
    const int bx = blockIdx.x, tid = threadIdx.x;
    if (bx < 512) {
        const float2 v = *(const float2*)(Wi + (size_t)bx * 512 + 2 * tid);
        WpkT[(size_t)bx * 256 + tid] = pack2h(v.x, v.y);
    } else {
        const int p = bx - 512;
        #pragma unroll
        for (int r = 0; r < 2; ++r) {
            const int d = tid + 256 * r;
            Wypk[(size_t)p * 512 + d] =
                pack2h(Wy[(size_t)d * 512 + 2 * p], Wy[(size_t)d * 512 + 2 * p + 1]);
        }
    }
}

// ---------------------------------------------------------------------------
// K1: gate pre-activations (parallel over all t). Unchanged.
// ---------------------------------------------------------------------------
__global__ __launch_bounds__(256) void k1_gates(
    const float* __restrict__ word,
    const float* __restrict__ Wi, const float* __restrict__ Wz, const float* __restrict__ Wo,
    const float* __restrict__ bi, const float* __restrict__ bz, const float* __restrict__ bo,
    u16* __restrict__ Xi, u16* __restrict__ Xz, u16* __restrict__ Xo)
{
    __shared__ uint4 ws2v[3][128][4];
    __shared__ u32 xs2[2][16][36];

    const int tid = threadIdx.x;
    const int d_l = tid & 63;
    const int bq  = tid >> 6;
    const int t0  = blockIdx.x * 2;
    const int d0  = blockIdx.y * 128;

    const float* Wg[3] = {Wi, Wz, Wo};

    float acc[2][2][8][3];
    #pragma unroll
    for (int tt = 0; tt < 2; ++tt)
        #pragma unroll
        for (int db = 0; db < 2; ++db)
            #pragma unroll
            for (int j = 0; j < 8; ++j)
                #pragma unroll
                for (int g = 0; g < 3; ++g) acc[tt][db][j][g] = 0.0f;

    for (int k0c = 0; k0c < 512; k0c += 32) {
        {
            const int p = tid & 15, bg = tid >> 4;
            #pragma unroll
            for (int tt = 0; tt < 2; ++tt)
                #pragma unroll
                for (int j = 0; j < 2; ++j) {
                    const int bb = bg * 2 + j;
                    const float2 v = *(const float2*)(word + (((size_t)(t0 + tt) * 32 + bb) * 512 + k0c + 2 * p));
                    xs2[tt][p][bb] = pack2h(v.x, v.y);
                }
        }
        {
            #pragma unroll
            for (int cc = 0; cc < 6; ++cc) {
                const int c = tid + 256 * cc;
                const int g = c >> 9, r = c & 511, pg = r >> 7, i = r & 127;
                const float* src = Wg[g] + (size_t)(d0 + i) * 512 + k0c + 8 * pg;
                const float4 v0 = ((const float4*)src)[0];
                const float4 v1 = ((const float4*)src)[1];
                uint4 cell;
                cell.x = pack2h(v0.x, v0.y); cell.y = pack2h(v0.z, v0.w);
                cell.z = pack2h(v1.x, v1.y); cell.w = pack2h(v1.z, v1.w);
                ws2v[g][i][(pg + (i >> 2)) & 3] = cell;
            }
        }
        __syncthreads();
        #pragma unroll
        for (int pg = 0; pg < 4; ++pg) {
            uint4 wc[3][2];
            #pragma unroll
            for (int g = 0; g < 3; ++g)
                #pragma unroll
                for (int db = 0; db < 2; ++db) {
                    const int d = d_l + 64 * db;
                    wc[g][db] = ws2v[g][d][(pg + (d >> 2)) & 3];
                }
            #pragma unroll
            for (int p = 0; p < 4; ++p) {
                const int pair = 4 * pg + p;
                u32 x2[2][8];
                #pragma unroll
                for (int tt = 0; tt < 2; ++tt) {
                    const uint4* xr = (const uint4*)&xs2[tt][pair][bq * 8];
                    uint4 xa = xr[0], xb = xr[1];
                    x2[tt][0] = xa.x; x2[tt][1] = xa.y; x2[tt][2] = xa.z; x2[tt][3] = xa.w;
                    x2[tt][4] = xb.x; x2[tt][5] = xb.y; x2[tt][6] = xb.z; x2[tt][7] = xb.w;
                }
                u32 w[3][2];
                #pragma unroll
                for (int g = 0; g < 3; ++g)
                    #pragma unroll
                    for (int db = 0; db < 2; ++db) {
                        const uint4 v = wc[g][db];
                        w[g][db] = (p == 0) ? v.x : (p == 1) ? v.y : (p == 2) ? v.z : v.w;
                    }
                #pragma unroll
                for (int tt = 0; tt < 2; ++tt)
                    #pragma unroll
                    for (int db = 0; db < 2; ++db)
                        #pragma unroll
                        for (int j = 0; j < 8; ++j)
                            #pragma unroll
                            for (int g = 0; g < 3; ++g)
                                acc[tt][db][j][g] = fdot2(x2[tt][j], w[g][db], acc[tt][db][j][g]);
            }
        }
        __syncthreads();
    }

    #pragma unroll
    for (int db = 0; db < 2; ++db) {
        const int d = d0 + 64 * db + d_l;
        const float b0 = 2.0f * bi[d];
        const float b1 = bz[d] + bi[d];
        const float b2 = bo[d] + bi[d];
        #pragma unroll
        for (int tt = 0; tt < 2; ++tt)
            #pragma unroll
            for (int j = 0; j < 8; ++j) {
                const size_t o = ((size_t)(t0 + tt) * 32 + (bq * 8 + j)) * 512 + d;
                Xi[o] = f2h(acc[tt][db][j][0] + b0);
                Xz[o] = f2h(acc[tt][db][j][1] + b1);
                Xo[o] = f2h(acc[tt][db][j][2] + b2);
            }
    }
}

// ---------------------------------------------------------------------------
// K2 v11: v10 structure with register CLASSES matched to the unified file.
// Post-mortem v10: at 2 waves/SIMD the per-wave cap is 256 TOTAL regs
// (arch VGPR + AGPR share the 512-reg/SIMD pool). v10 pinned 192 u32 "+v"
// (arch class); the RA split 128v+128a and inserted accvgpr shuffles around
// every pin -> measured ~2640 cy/step of VALU issue vs ~1180 ideal.
// v11: rows 0..3 (128 u32) pinned "+v" (arch demand 128+~45=173 <= 256 OK),
// rows 4..5 (64 u32) pinned "+a" (AGPR class; CDNA VALU can source AGPRs,
// worst case 64 v_accvgpr_read/step). Total 237 <= 256 -> feasible, no
// forced shuffle. Rows 6..7 stay LDS-streamed exactly as v10 (the ~2300 cy
// LDS floor; VALU now hides under it). Arithmetic identical to v10.
// ---------------------------------------------------------------------------
#define PINV(x) asm volatile("" : "+v"(x));
#define PINA(x) asm volatile("" : "+a"(x));

#define ROWV(r) \
    const u32x4* wp##r = (const u32x4*)(WpkT + ((size_t)(8 * dg + r) * 256 + 32 * ks)); \
    u32x4 W##r##0 = wp##r[0], W##r##1 = wp##r[1], W##r##2 = wp##r[2], W##r##3 = wp##r[3], \
          W##r##4 = wp##r[4], W##r##5 = wp##r[5], W##r##6 = wp##r[6], W##r##7 = wp##r[7]; \
    PINV(W##r##0) PINV(W##r##1) PINV(W##r##2) PINV(W##r##3) \
    PINV(W##r##4) PINV(W##r##5) PINV(W##r##6) PINV(W##r##7)

#define ROWA(r) \
    const u32x4* wp##r = (const u32x4*)(WpkT + ((size_t)(8 * dg + r) * 256 + 32 * ks)); \
    u32x4 W##r##0 = wp##r[0], W##r##1 = wp##r[1], W##r##2 = wp##r[2], W##r##3 = wp##r[3], \
          W##r##4 = wp##r[4], W##r##5 = wp##r[5], W##r##6 = wp##r[6], W##r##7 = wp##r[7]; \
    PINA(W##r##0) PINA(W##r##1) PINA(W##r##2) PINA(W##r##3) \
    PINA(W##r##4) PINA(W##r##5) PINA(W##r##6) PINA(W##r##7)

#define DOT4(A, hc, wv) \
    A = fdot2(hc.x, (wv).x, A); A = fdot2(hc.y, (wv).y, A); \
    A = fdot2(hc.z, (wv).z, A); A = fdot2(hc.w, (wv).w, A);

#define CCBLK(cc) { \
    const uint4 hc  = hv[cc]; \
    const uint4 wl6 = wl[cc][tid]; \
    const uint4 wl7 = wl[8 + cc][tid]; \
    DOT4(a0, hc, W0##cc)  DOT4(a1, hc, W1##cc)  DOT4(a2, hc, W2##cc) \
    DOT4(a3, hc, W3##cc)  DOT4(a4, hc, W4##cc)  DOT4(a5, hc, W5##cc) \
    DOT4(a6, hc, wl6)     DOT4(a7, hc, wl7) }

#define HSTR 72   // u16 stride per 64-element h slice (144 B; v7-proven, 0 conflicts)

__global__ __launch_bounds__(512)
__attribute__((amdgpu_waves_per_eu(2, 2)))
void k2_recur(
    const u16* __restrict__ Xi, const u16* __restrict__ Xz, const u16* __restrict__ Xo,
    const u32* __restrict__ WpkT, const u32* __restrict__ Wypk,
    const float* __restrict__ by, float* __restrict__ out)
{
    __shared__ uint4 wl[16][512];                 // 128 KB: LDS-resident rows 6..7
    __shared__ alignas(16) u16 hb[2][8 * HSTR];   // strided h, f16, ping-pong

    const int b   = blockIdx.x;                   // 0..31
    const int tid = threadIdx.x;
    const int dg  = tid >> 3;                     // output group (8 rows), 0..63
    const int ks  = tid & 7;                      // K-slice (32 pairs)

    // weight rows 0..3 -> arch VGPRs, rows 4..5 -> AGPRs (unified-file split)
    ROWV(0) ROWV(1) ROWV(2) ROWV(3) ROWA(4) ROWA(5)

    // stage LDS-resident rows 6..7: wl[rr*8+cc][tid]
    #pragma unroll
    for (int rr = 0; rr < 2; ++rr) {
        const uint4* src = (const uint4*)(WpkT + ((size_t)(8 * dg + 6 + rr) * 256 + 32 * ks));
        #pragma unroll
        for (int cc = 0; cc < 8; ++cc) wl[rr * 8 + cc][tid] = src[cc];
    }

    // h = 0 at t = 0 (zero both ping-pong buffers incl. pads)
    for (int i = tid; i < 2 * 8 * HSTR; i += 512) ((u16*)hb)[i] = (u16)0;
    __syncthreads();

    // this thread owns output d == tid after the butterfly
    u16 xi_c = Xi[(size_t)b * 512 + tid];
    u16 xz_c = Xz[(size_t)b * 512 + tid];
    u16 xo_c = Xo[(size_t)b * 512 + tid];

    const int hwr = (tid >> 6) * HSTR + (tid & 63);   // strided publish slot
    const int sb0 = tid & 1, sb1 = tid & 2, sb2 = tid & 4;

    for (int t = 0; t < 2048; ++t) {
        const int par = t & 1;

        // prefetch next-step x (latency hides under the dot)
        const int tn = (t + 1) & 2047;
        const size_t xb = ((size_t)tn * 32 + b) * 512 + tid;
        const u16 xi_n = Xi[xb], xz_n = Xz[xb], xo_n = Xo[xb];

        // 8 partial dots over this thread's 32-pair K-slice
        const uint4* hv = (const uint4*)((const char*)&hb[par][0] + ks * 144);
        float a0 = 0.f, a1 = 0.f, a2 = 0.f, a3 = 0.f,
              a4 = 0.f, a5 = 0.f, a6 = 0.f, a7 = 0.f;
        CCBLK(0) CCBLK(1) CCBLK(2) CCBLK(3)
        CCBLK(4) CCBLK(5) CCBLK(6) CCBLK(7)

        // 3-stage in-wave butterfly over the 8-lane group (v7-proven):
        // lane ks ends with the full dot for output 8dg+ks == tid.
        float q0, q1, q2, q3;
        {
            float s, k;
            s = sb0 ? a0 : a1; k = sb0 ? a1 : a0; q0 = k + __shfl_xor(s, 1);
            s = sb0 ? a2 : a3; k = sb0 ? a3 : a2; q1 = k + __shfl_xor(s, 1);
            s = sb0 ? a4 : a5; k = sb0 ? a5 : a4; q2 = k + __shfl_xor(s, 1);
            s = sb0 ? a6 : a7; k = sb0 ? a7 : a6; q3 = k + __shfl_xor(s, 1);
        }
        float r0, r1;
        {
            float s, k;
            s = sb1 ? q0 : q1; k = sb1 ? q1 : q0; r0 = k + __shfl_xor(s, 2);
            s = sb1 ? q2 : q3; k = sb1 ? q3 : q2; r1 = k + __shfl_xor(s, 2);
        }
        float v;
        {
            float s = sb2 ? r0 : r1, k = sb2 ? r1 : r0;
            v = k + __shfl_xor(s, 4);
        }

        const float zi = fsigmoid(h2f(xi_c) + v);
        const float z  = fsigmoid(h2f(xz_c) + v);
        const float zo = fsigmoid(h2f(xo_c) + v);
        const float hn = zo * ftanh_pos(zi * z);

        hb[par ^ 1][hwr] = f2h(hn);          // publish h for step t+1
        __syncthreads();                     // single barrier per step

        xi_c = xi_n; xz_c = xz_n; xo_c = xo_n;
    }

    // epilogue: final h is in hb[0] (t=2047, par=1 wrote hb[0]).
    // Same accumulation order as v7/v9b/v10 (global chunk i = 8s+c ascending).
    {
        float e0 = 0.f, e1 = 0.f, e2 = 0.f, e3 = 0.f;
        #pragma unroll
        for (int s = 0; s < 8; ++s) {
            const uint4* hv0 = (const uint4*)((const char*)&hb[0][0] + s * 144);
            #pragma unroll
            for (int c = 0; c < 8; ++c) {
                const uint4 hc = hv0[c];
                const int i = 8 * s + c;
                e0 = fdot2(hc.x, Wypk[(size_t)(4 * i + 0) * 512 + tid], e0);
                e1 = fdot2(hc.y, Wypk[(size_t)(4 * i + 1) * 512 + tid], e1);
                e2 = fdot2(hc.z, Wypk[(size_t)(4 * i + 2) * 512 + tid], e2);
                e3 = fdot2(hc.w, Wypk[(size_t)(4 * i + 3) * 512 + tid], e3);
            }
        }
        out[(size_t)b * 512 + tid] = (e0 + e1) + (e2 + e3) + by[tid];
    }
}

// ---------------------------------------------------------------------------
extern "C" void kernel_launch(void* const* d_in, const int* in_sizes, int n_in,
                              void* d_out, int out_size, void* d_ws, size_t ws_size,
                              hipStream_t stream) {
    const float* word = (const float*)d_in[0];
    // d_in[1]=Wf, d_in[2]=bf : dead in the reference (c==0 path), unused.
    const float* Wi = (const float*)d_in[3];
    const float* bi = (const float*)d_in[4];
    const float* Wz = (const float*)d_in[5];
    const float* bz = (const float*)d_in[6];
    const float* Wo = (const float*)d_in[7];
    const float* bo = (const float*)d_in[8];
    const float* Wy = (const float*)d_in[9];
    const float* by = (const float*)d_in[10];
    float* out = (float*)d_out;

    char* ws = (char*)d_ws;
    const size_t XN = (size_t)2048 * 32 * 512 * sizeof(u16);  // 64 MB per gate array
    u16* Xi = (u16*)(ws);
    u16* Xz = (u16*)(ws + XN);
    u16* Xo = (u16*)(ws + 2 * XN);
    u32* WpkT = (u32*)(ws + 3 * XN);                          // 512 KB
    u32* Wypk = (u32*)(ws + 3 * XN + (size_t)524288);         // 512 KB

    k0_pack<<<768, 256, 0, stream>>>(Wi, Wy, WpkT, Wypk);

    dim3 g1(1024, 4);
    k1_gates<<<g1, 256, 0, stream>>>(word, Wi, Wz, Wo, bi, bz, bo, Xi, Xz, Xo);

    k2_recur<<<32, 512, 0, stream>>>(Xi, Xz, Xo, WpkT, Wypk, by, out);
}